// Round 8
// baseline (445.769 us; speedup 1.0000x reference)
//
#include <hip/hip_runtime.h>
#include <math.h>

#define NB 64
#define TPB 256

// 1/k! for k = 0..13 (degree-13 Taylor)
__device__ __constant__ float CF[16] = {
    1.0f,
    1.0f,
    0.5f,
    1.6666666666666666e-01f,
    4.1666666666666664e-02f,
    8.3333333333333332e-03f,
    1.3888888888888889e-03f,
    1.9841269841269841e-04f,
    2.4801587301587302e-05f,
    2.7557319223985893e-06f,
    2.7557319223985888e-07f,
    2.5052108385441720e-08f,
    2.0876756987868100e-09f,
    1.6059043836821613e-10f,
    1.1470745597729725e-11f,
    7.6471637318198164e-13f
};

typedef __attribute__((ext_vector_type(8))) short bf16x8;
typedef __attribute__((ext_vector_type(16))) float f32x16;
typedef __attribute__((ext_vector_type(4))) unsigned int u32x4;

#define MFMA32 __builtin_amdgcn_mfma_f32_32x32x16_bf16

// packed split: (x0,x1) -> hi word (bf16(x0)|bf16(x1)<<16), lo word (residuals)
__device__ __forceinline__ void split_pk(float x0, float x1, unsigned& ph, unsigned& pl) {
    unsigned h;
    asm("v_cvt_pk_bf16_f32 %0, %1, %2" : "=v"(h) : "v"(x0), "v"(x1));
    float h0 = __builtin_bit_cast(float, h << 16);
    float h1 = __builtin_bit_cast(float, h & 0xFFFF0000u);
    float r0 = x0 - h0;
    float r1 = x1 - h1;
    unsigned l;
    asm("v_cvt_pk_bf16_f32 %0, %1, %2" : "=v"(l) : "v"(r0), "v"(r1));
    ph = h; pl = l;
}

__device__ __forceinline__ float bf2f(unsigned short h) {
    unsigned u = ((unsigned)h) << 16;
    return __builtin_bit_cast(float, u);
}

// byte offset of (row, byteInRow) in a swizzled 64x64 bf16 LDS matrix (128 B rows)
__device__ __forceinline__ unsigned swzoff(int row, int byteInRow) {
    return (unsigned)(row * 128 + (byteInRow ^ ((row & 7) << 4)));
}

// A/B fragment for v_mfma_f32_32x32x16_bf16, k-step f (k in [16f,16f+16)).
// lane: row = rowbase + (lane&31), k = 16f + 8*(lane>>5) + 0..7  -> 16B read.
__device__ __forceinline__ bf16x8 ldfrag(const unsigned short* buf, int row, int f, int lh) {
    const char* p = (const char*)buf + swzoff(row, f * 32 + lh * 16);
    return __builtin_bit_cast(bf16x8, *(const u32x4*)p);
}

// acc = Ahi*Bhi + Alo*Bhi + Ahi*Blo  over K=64 (4 k-steps each)
__device__ __forceinline__ f32x16 mm3(const bf16x8* ah, const bf16x8* al,
                                      const bf16x8* bh, const bf16x8* bl) {
    f32x16 acc = {};
#pragma unroll
    for (int f = 0; f < 4; ++f) acc = MFMA32(ah[f], bh[f], acc, 0, 0, 0);
#pragma unroll
    for (int f = 0; f < 4; ++f) acc = MFMA32(al[f], bh[f], acc, 0, 0, 0);
#pragma unroll
    for (int f = 0; f < 4; ++f) acc = MFMA32(ah[f], bl[f], acc, 0, 0, 0);
    return acc;
}

// Split v[16] into hi/lo bf16 and write TRANSPOSED: value (row r_out, col c_out)
// goes to LDS[c_out][r_out]; 4 consecutive rows per reg-group -> one ds_write_b64.
__device__ __forceinline__ void store_cT(unsigned short* Bh, unsigned short* Bl,
                                         const float* v, int c_out, int rbase) {
#pragma unroll
    for (int g = 0; g < 4; ++g) {
        uint2 wh, wl;
        split_pk(v[g * 4 + 0], v[g * 4 + 1], wh.x, wl.x);
        split_pk(v[g * 4 + 2], v[g * 4 + 3], wh.y, wl.y);
        unsigned off = swzoff(c_out, (rbase + g * 8) * 2);
        *(uint2*)((char*)Bh + off) = wh;
        *(uint2*)((char*)Bl + off) = wl;
    }
}

__global__ __launch_bounds__(TPB, 5)
void spd_expmap_mfma(const float* __restrict__ in, float* __restrict__ out)
{
    // Exactly 32 KiB LDS -> 5 blocks/CU (160 KiB / 32 KiB).
    // B0 = X, later P (ping).  B1 = Frobenius scratch, then Y, later P (pong).
    __shared__ __align__(16) unsigned short SB[4 * 4096];
    unsigned short* B0h = SB;
    unsigned short* B0l = SB + 4096;
    unsigned short* B1h = SB + 8192;
    unsigned short* B1l = SB + 12288;
    float* fscratch = (float*)B1h;     // 4 floats, dead until Y is stored

    const int tid  = threadIdx.x;
    const int lane = tid & 63;
    const int wv   = tid >> 6;
    const int wr   = (wv >> 1) * 32;   // wave's output row-block
    const int wc   = (wv & 1) * 32;    // wave's output col-block
    const int l31  = lane & 31;
    const int lh   = lane >> 5;
    const int c_out = wc + l31;                 // C/D: col = lane&31
    const int rbase = wr + 4 * lh;              // C/D: row = (reg&3)+8*(reg>>2)+4*(lane>>5)
    const size_t base = (size_t)blockIdx.x * (NB * NB);
    const bool diag = (wr == wc);

    unsigned dmask = 0;
#pragma unroll
    for (int g = 0; g < 4; ++g)
#pragma unroll
        for (int q = 0; q < 4; ++q)
            if (rbase + g * 8 + q == c_out) dmask |= 1u << (g * 4 + q);

    // ---- load A (fp32), split hi/lo (packed cvt), store swizzled into B0 ----
    {
        const int r  = tid >> 2;
        const int cb = (tid & 3) * 16;
        const float4* gp = (const float4*)(in + base) + tid * 4;
        float vv[16];
#pragma unroll
        for (int i = 0; i < 4; ++i) {
            float4 t = gp[i];
            vv[i * 4 + 0] = t.x; vv[i * 4 + 1] = t.y;
            vv[i * 4 + 2] = t.z; vv[i * 4 + 3] = t.w;
        }
        unsigned hw[8], lw[8];
#pragma unroll
        for (int i = 0; i < 8; ++i)
            split_pk(vv[2 * i], vv[2 * i + 1], hw[i], lw[i]);
        u32x4 H0 = {hw[0], hw[1], hw[2], hw[3]}, H1 = {hw[4], hw[5], hw[6], hw[7]};
        u32x4 L0 = {lw[0], lw[1], lw[2], lw[3]}, L1 = {lw[4], lw[5], lw[6], lw[7]};
        unsigned o0 = swzoff(r, cb * 2), o1 = swzoff(r, cb * 2 + 16);
        *(u32x4*)((char*)B0h + o0) = H0; *(u32x4*)((char*)B0h + o1) = H1;
        *(u32x4*)((char*)B0l + o0) = L0; *(u32x4*)((char*)B0l + o1) = L1;
    }
    __syncthreads();   // S1: X visible

    // ---- mm1: acc = A*A (split product) + per-wave Frobenius partial ----
    f32x16 acc;
    {
        bf16x8 ah[4], al[4], bh[4], bl[4];
#pragma unroll
        for (int f = 0; f < 4; ++f) {
            ah[f] = ldfrag(B0h, wr + l31, f, lh);
            al[f] = ldfrag(B0l, wr + l31, f, lh);
        }
        if (diag) {
#pragma unroll
            for (int f = 0; f < 4; ++f) { bh[f] = ah[f]; bl[f] = al[f]; }
        } else {
#pragma unroll
            for (int f = 0; f < 4; ++f) {
                bh[f] = ldfrag(B0h, wc + l31, f, lh);
                bl[f] = ldfrag(B0l, wc + l31, f, lh);
            }
        }
        acc = mm3(ah, al, bh, bl);
        float fr = 0.f;
#pragma unroll
        for (int r = 0; r < 16; ++r) fr += acc[r] * acc[r];
#pragma unroll
        for (int off = 32; off; off >>= 1) fr += __shfl_xor(fr, off);
        if (lane == 0) fscratch[wv] = fr;
    }
    __syncthreads();   // S2: partials visible; B0 frag reads drained

    // ||A||_2 <= (sum (A^2)_ij^2)^(1/4); tolerate ||X|| <= 4 (deg-13 remainder ok)
    const float total = fscratch[0] + fscratch[1] + fscratch[2] + fscratch[3];
    __syncthreads();   // S3: all read fscratch before Y overwrites B1
    const float bound = sqrtf(sqrtf(total));
    int sexp = 0;
    if (bound > 4.f) {
        sexp = (int)ceilf(log2f(bound)) - 2;
        if (sexp < 0) sexp = 0;
        if (sexp > 24) sexp = 24;
    }
    const float sc1 = exp2f(-(float)sexp);
    const float sc2 = sc1 * sc1;

    // ---- Y = acc * 4^-s -> split-store into B1 (pre-scaled) ----
    {
        float v[16];
#pragma unroll
        for (int r = 0; r < 16; ++r) v[r] = acc[r] * sc2;
        store_cT(B1h, B1l, v, c_out, rbase);
    }

    // ---- x_out: X at this lane's OWN output positions, scaled in regs ----
    float x_out[16];
#pragma unroll
    for (int g = 0; g < 4; ++g) {
        unsigned off = swzoff(c_out, (rbase + g * 8) * 2);
        uint2 xh = *(const uint2*)((const char*)B0h + off);
        uint2 xl = *(const uint2*)((const char*)B0l + off);
        x_out[g * 4 + 0] = (bf2f((unsigned short)(xh.x & 0xFFFF)) + bf2f((unsigned short)(xl.x & 0xFFFF))) * sc1;
        x_out[g * 4 + 1] = (bf2f((unsigned short)(xh.x >> 16))    + bf2f((unsigned short)(xl.x >> 16)))    * sc1;
        x_out[g * 4 + 2] = (bf2f((unsigned short)(xh.y & 0xFFFF)) + bf2f((unsigned short)(xl.y & 0xFFFF))) * sc1;
        x_out[g * 4 + 3] = (bf2f((unsigned short)(xh.y >> 16))    + bf2f((unsigned short)(xl.y >> 16)))    * sc1;
    }

    // ---- P init = CF[12]*I + CF[13]*X -> B0 (own positions only; X consumed) ----
    {
        float v[16];
#pragma unroll
        for (int r = 0; r < 16; ++r)
            v[r] = CF[13] * x_out[r] + (((dmask >> r) & 1) ? CF[12] : 0.f);
        store_cT(B0h, B0l, v, c_out, rbase);
    }
    __syncthreads();   // S4: Y (B1) + P-init (B0) visible

    // ---- resident Y A-side fragments ----
    bf16x8 ya_h[4], ya_l[4];
#pragma unroll
    for (int f = 0; f < 4; ++f) {
        ya_h[f] = ldfrag(B1h, wr + l31, f, lh);
        ya_l[f] = ldfrag(B1l, wr + l31, f, lh);
    }
    __syncthreads();   // S5: Y-frag reads drained before Horner overwrites B1

    // ---- Horner (degree-13, chunk-2):  P <- (c2j*I + c2j+1*X) + Y*P,  j = 5..0 ----
    unsigned short* curh = B0h; unsigned short* curl = B0l;
    unsigned short* nxth = B1h; unsigned short* nxtl = B1l;
#pragma unroll 1
    for (int j = 5; j >= 0; --j) {
        bf16x8 pbh[4], pbl[4];
#pragma unroll
        for (int f = 0; f < 4; ++f) {
            pbh[f] = ldfrag(curh, wc + l31, f, lh);
            pbl[f] = ldfrag(curl, wc + l31, f, lh);
        }
        f32x16 a2 = mm3(ya_h, ya_l, pbh, pbl);
        float w[16];
        const float cI = CF[2 * j], cX = CF[2 * j + 1];
#pragma unroll
        for (int r = 0; r < 16; ++r)
            w[r] = a2[r] + cX * x_out[r] + (((dmask >> r) & 1) ? cI : 0.f);
        store_cT(nxth, nxtl, w, c_out, rbase);
        unsigned short* th = curh; curh = nxth; nxth = th;
        unsigned short* tl = curl; curl = nxtl; nxtl = tl;
        __syncthreads();   // one barrier per stage (ping-pong)
    }

    // ---- s squarings: P <- P*P; final result written straight to global ----
#pragma unroll 1
    for (int t = 0; t < sexp; ++t) {
        bf16x8 pah[4], pal[4], pbh[4], pbl[4];
#pragma unroll
        for (int f = 0; f < 4; ++f) {
            pah[f] = ldfrag(curh, wr + l31, f, lh);
            pal[f] = ldfrag(curl, wr + l31, f, lh);
        }
        if (diag) {
#pragma unroll
            for (int f = 0; f < 4; ++f) { pbh[f] = pah[f]; pbl[f] = pal[f]; }
        } else {
#pragma unroll
            for (int f = 0; f < 4; ++f) {
                pbh[f] = ldfrag(curh, wc + l31, f, lh);
                pbl[f] = ldfrag(curl, wc + l31, f, lh);
            }
        }
        f32x16 a2 = mm3(pah, pal, pbh, pbl);
        if (t == sexp - 1) {
            // final: fp32 straight from acc (col-contiguous across lanes -> coalesced)
#pragma unroll
            for (int g = 0; g < 4; ++g)
#pragma unroll
                for (int q = 0; q < 4; ++q)
                    out[base + (size_t)(rbase + g * 8 + q) * NB + c_out] = a2[g * 4 + q];
        } else {
            store_cT(nxth, nxtl, (const float*)&a2, c_out, rbase);
            unsigned short* th = curh; curh = nxth; nxth = th;
            unsigned short* tl = curl; curl = nxtl; nxtl = tl;
            __syncthreads();
        }
    }

    if (sexp == 0) {
        // No squarings: P (hi+lo in cur) is the answer; own positions, no barrier needed.
#pragma unroll
        for (int g = 0; g < 4; ++g) {
            unsigned off = swzoff(c_out, (rbase + g * 8) * 2);
            uint2 ph = *(const uint2*)((const char*)curh + off);
            uint2 pl = *(const uint2*)((const char*)curl + off);
            float v0 = bf2f((unsigned short)(ph.x & 0xFFFF)) + bf2f((unsigned short)(pl.x & 0xFFFF));
            float v1 = bf2f((unsigned short)(ph.x >> 16))    + bf2f((unsigned short)(pl.x >> 16));
            float v2 = bf2f((unsigned short)(ph.y & 0xFFFF)) + bf2f((unsigned short)(pl.y & 0xFFFF));
            float v3 = bf2f((unsigned short)(ph.y >> 16))    + bf2f((unsigned short)(pl.y >> 16));
            out[base + (size_t)(rbase + g * 8 + 0) * NB + c_out] = v0;
            out[base + (size_t)(rbase + g * 8 + 1) * NB + c_out] = v1;
            out[base + (size_t)(rbase + g * 8 + 2) * NB + c_out] = v2;
            out[base + (size_t)(rbase + g * 8 + 3) * NB + c_out] = v3;
        }
    }
}

extern "C" void kernel_launch(void* const* d_in, const int* in_sizes, int n_in,
                              void* d_out, int out_size, void* d_ws, size_t ws_size,
                              hipStream_t stream) {
    const float* in = reinterpret_cast<const float*>(d_in[0]);
    float* out = reinterpret_cast<float*>(d_out);
    const int nmat = in_sizes[0] / (NB * NB);
    hipLaunchKernelGGL(spd_expmap_mfma, dim3(nmat), dim3(TPB), 0, stream, in, out);
}

// Round 9
// 306.610 us; speedup vs baseline: 1.4539x; 1.4539x over previous
//
#include <hip/hip_runtime.h>
#include <math.h>

#define NB 64
#define TPB 256

// 1/k! for k = 0..13 (degree-13 Taylor)
__device__ __constant__ float CF[16] = {
    1.0f,
    1.0f,
    0.5f,
    1.6666666666666666e-01f,
    4.1666666666666664e-02f,
    8.3333333333333332e-03f,
    1.3888888888888889e-03f,
    1.9841269841269841e-04f,
    2.4801587301587302e-05f,
    2.7557319223985893e-06f,
    2.7557319223985888e-07f,
    2.5052108385441720e-08f,
    2.0876756987868100e-09f,
    1.6059043836821613e-10f,
    1.1470745597729725e-11f,
    7.6471637318198164e-13f
};

typedef __attribute__((ext_vector_type(8))) short bf16x8;
typedef __attribute__((ext_vector_type(16))) float f32x16;
typedef __attribute__((ext_vector_type(4))) unsigned int u32x4;

#define MFMA32 __builtin_amdgcn_mfma_f32_32x32x16_bf16

// packed split: (x0,x1) -> hi word (bf16(x0)|bf16(x1)<<16), lo word (residuals)
__device__ __forceinline__ void split_pk(float x0, float x1, unsigned& ph, unsigned& pl) {
    unsigned h;
    asm("v_cvt_pk_bf16_f32 %0, %1, %2" : "=v"(h) : "v"(x0), "v"(x1));
    float h0 = __builtin_bit_cast(float, h << 16);
    float h1 = __builtin_bit_cast(float, h & 0xFFFF0000u);
    float r0 = x0 - h0;
    float r1 = x1 - h1;
    unsigned l;
    asm("v_cvt_pk_bf16_f32 %0, %1, %2" : "=v"(l) : "v"(r0), "v"(r1));
    ph = h; pl = l;
}

__device__ __forceinline__ float bf2f(unsigned short h) {
    unsigned u = ((unsigned)h) << 16;
    return __builtin_bit_cast(float, u);
}

// byte offset of (row, byteInRow) in a swizzled 64x64 bf16 LDS matrix (128 B rows)
__device__ __forceinline__ unsigned swzoff(int row, int byteInRow) {
    return (unsigned)(row * 128 + (byteInRow ^ ((row & 7) << 4)));
}

// A/B fragment for v_mfma_f32_32x32x16_bf16, k-step f (k in [16f,16f+16)).
// lane: row = rowbase + (lane&31), k = 16f + 8*(lane>>5) + 0..7  -> 16B read.
__device__ __forceinline__ bf16x8 ldfrag(const unsigned short* buf, int row, int f, int lh) {
    const char* p = (const char*)buf + swzoff(row, f * 32 + lh * 16);
    return __builtin_bit_cast(bf16x8, *(const u32x4*)p);
}

// acc = Ahi*Bhi + Alo*Bhi + Ahi*Blo  over K=64 (4 k-steps each)
__device__ __forceinline__ f32x16 mm3(const bf16x8* ah, const bf16x8* al,
                                      const bf16x8* bh, const bf16x8* bl) {
    f32x16 acc = {};
#pragma unroll
    for (int f = 0; f < 4; ++f) acc = MFMA32(ah[f], bh[f], acc, 0, 0, 0);
#pragma unroll
    for (int f = 0; f < 4; ++f) acc = MFMA32(al[f], bh[f], acc, 0, 0, 0);
#pragma unroll
    for (int f = 0; f < 4; ++f) acc = MFMA32(ah[f], bl[f], acc, 0, 0, 0);
    return acc;
}

// Split v[16] into hi/lo bf16 and write TRANSPOSED: value (row r_out, col c_out)
// goes to LDS[c_out][r_out]; 4 consecutive rows per reg-group -> one ds_write_b64.
__device__ __forceinline__ void store_cT(unsigned short* Bh, unsigned short* Bl,
                                         const float* v, int c_out, int rbase) {
#pragma unroll
    for (int g = 0; g < 4; ++g) {
        uint2 wh, wl;
        split_pk(v[g * 4 + 0], v[g * 4 + 1], wh.x, wl.x);
        split_pk(v[g * 4 + 2], v[g * 4 + 3], wh.y, wl.y);
        unsigned off = swzoff(c_out, (rbase + g * 8) * 2);
        *(uint2*)((char*)Bh + off) = wh;
        *(uint2*)((char*)Bl + off) = wl;
    }
}

// launch_bounds(256,4): R8 showed (256,5) forces VGPR 64->48 WITH SCRATCH SPILLS
// (FETCH 131->422MB, WRITE 262->917MB). Keep compiler at 4 waves/EU budget;
// runtime occupancy is resource-min: VGPR 64 allows 8 w/SIMD, LDS 32KiB allows
// 5 blocks/CU -> hardware reaches 5 blocks/CU without spills.
__global__ __launch_bounds__(TPB, 4)
void spd_expmap_mfma(const float* __restrict__ in, float* __restrict__ out)
{
    // Exactly 32 KiB LDS -> 5 blocks/CU (160 KiB / 32 KiB).
    // B0 = X, later P (ping).  B1 = Frobenius scratch, then Y, later P (pong).
    __shared__ __align__(16) unsigned short SB[4 * 4096];
    unsigned short* B0h = SB;
    unsigned short* B0l = SB + 4096;
    unsigned short* B1h = SB + 8192;
    unsigned short* B1l = SB + 12288;
    float* fscratch = (float*)B1h;     // 4 floats, dead until Y is stored

    const int tid  = threadIdx.x;
    const int lane = tid & 63;
    const int wv   = tid >> 6;
    const int wr   = (wv >> 1) * 32;   // wave's output row-block
    const int wc   = (wv & 1) * 32;    // wave's output col-block
    const int l31  = lane & 31;
    const int lh   = lane >> 5;
    const int c_out = wc + l31;                 // C/D: col = lane&31
    const int rbase = wr + 4 * lh;              // C/D: row = (reg&3)+8*(reg>>2)+4*(lane>>5)
    const size_t base = (size_t)blockIdx.x * (NB * NB);
    const bool diag = (wr == wc);

    unsigned dmask = 0;
#pragma unroll
    for (int g = 0; g < 4; ++g)
#pragma unroll
        for (int q = 0; q < 4; ++q)
            if (rbase + g * 8 + q == c_out) dmask |= 1u << (g * 4 + q);

    // ---- load A (fp32), split hi/lo (packed cvt), store swizzled into B0 ----
    {
        const int r  = tid >> 2;
        const int cb = (tid & 3) * 16;
        const float4* gp = (const float4*)(in + base) + tid * 4;
        float vv[16];
#pragma unroll
        for (int i = 0; i < 4; ++i) {
            float4 t = gp[i];
            vv[i * 4 + 0] = t.x; vv[i * 4 + 1] = t.y;
            vv[i * 4 + 2] = t.z; vv[i * 4 + 3] = t.w;
        }
        unsigned hw[8], lw[8];
#pragma unroll
        for (int i = 0; i < 8; ++i)
            split_pk(vv[2 * i], vv[2 * i + 1], hw[i], lw[i]);
        u32x4 H0 = {hw[0], hw[1], hw[2], hw[3]}, H1 = {hw[4], hw[5], hw[6], hw[7]};
        u32x4 L0 = {lw[0], lw[1], lw[2], lw[3]}, L1 = {lw[4], lw[5], lw[6], lw[7]};
        unsigned o0 = swzoff(r, cb * 2), o1 = swzoff(r, cb * 2 + 16);
        *(u32x4*)((char*)B0h + o0) = H0; *(u32x4*)((char*)B0h + o1) = H1;
        *(u32x4*)((char*)B0l + o0) = L0; *(u32x4*)((char*)B0l + o1) = L1;
    }
    __syncthreads();   // S1: X visible

    // ---- mm1: acc = A*A (split product) + per-wave Frobenius partial ----
    f32x16 acc;
    {
        bf16x8 ah[4], al[4], bh[4], bl[4];
#pragma unroll
        for (int f = 0; f < 4; ++f) {
            ah[f] = ldfrag(B0h, wr + l31, f, lh);
            al[f] = ldfrag(B0l, wr + l31, f, lh);
        }
        if (diag) {
#pragma unroll
            for (int f = 0; f < 4; ++f) { bh[f] = ah[f]; bl[f] = al[f]; }
        } else {
#pragma unroll
            for (int f = 0; f < 4; ++f) {
                bh[f] = ldfrag(B0h, wc + l31, f, lh);
                bl[f] = ldfrag(B0l, wc + l31, f, lh);
            }
        }
        acc = mm3(ah, al, bh, bl);
        float fr = 0.f;
#pragma unroll
        for (int r = 0; r < 16; ++r) fr += acc[r] * acc[r];
#pragma unroll
        for (int off = 32; off; off >>= 1) fr += __shfl_xor(fr, off);
        if (lane == 0) fscratch[wv] = fr;
    }
    __syncthreads();   // S2: partials visible; B0 frag reads drained

    // ||A||_2 <= (sum (A^2)_ij^2)^(1/4); tolerate ||X|| <= 4 (deg-13 remainder ok)
    const float total = fscratch[0] + fscratch[1] + fscratch[2] + fscratch[3];
    __syncthreads();   // S3: all read fscratch before Y overwrites B1
    const float bound = sqrtf(sqrtf(total));
    int sexp = 0;
    if (bound > 4.f) {
        sexp = (int)ceilf(log2f(bound)) - 2;
        if (sexp < 0) sexp = 0;
        if (sexp > 24) sexp = 24;
    }
    const float sc1 = exp2f(-(float)sexp);
    const float sc2 = sc1 * sc1;

    // ---- Y = acc * 4^-s -> split-store into B1 (pre-scaled) ----
    {
        float v[16];
#pragma unroll
        for (int r = 0; r < 16; ++r) v[r] = acc[r] * sc2;
        store_cT(B1h, B1l, v, c_out, rbase);
    }

    // ---- x_out: X at this lane's OWN output positions, scaled in regs ----
    float x_out[16];
#pragma unroll
    for (int g = 0; g < 4; ++g) {
        unsigned off = swzoff(c_out, (rbase + g * 8) * 2);
        uint2 xh = *(const uint2*)((const char*)B0h + off);
        uint2 xl = *(const uint2*)((const char*)B0l + off);
        x_out[g * 4 + 0] = (bf2f((unsigned short)(xh.x & 0xFFFF)) + bf2f((unsigned short)(xl.x & 0xFFFF))) * sc1;
        x_out[g * 4 + 1] = (bf2f((unsigned short)(xh.x >> 16))    + bf2f((unsigned short)(xl.x >> 16)))    * sc1;
        x_out[g * 4 + 2] = (bf2f((unsigned short)(xh.y & 0xFFFF)) + bf2f((unsigned short)(xl.y & 0xFFFF))) * sc1;
        x_out[g * 4 + 3] = (bf2f((unsigned short)(xh.y >> 16))    + bf2f((unsigned short)(xl.y >> 16)))    * sc1;
    }

    // ---- P init = CF[12]*I + CF[13]*X -> B0 (own positions only; X consumed) ----
    {
        float v[16];
#pragma unroll
        for (int r = 0; r < 16; ++r)
            v[r] = CF[13] * x_out[r] + (((dmask >> r) & 1) ? CF[12] : 0.f);
        store_cT(B0h, B0l, v, c_out, rbase);
    }
    __syncthreads();   // S4: Y (B1) + P-init (B0) visible

    // ---- resident Y A-side fragments ----
    bf16x8 ya_h[4], ya_l[4];
#pragma unroll
    for (int f = 0; f < 4; ++f) {
        ya_h[f] = ldfrag(B1h, wr + l31, f, lh);
        ya_l[f] = ldfrag(B1l, wr + l31, f, lh);
    }
    __syncthreads();   // S5: Y-frag reads drained before Horner overwrites B1

    // ---- Horner (degree-13, chunk-2):  P <- (c2j*I + c2j+1*X) + Y*P,  j = 5..0 ----
    unsigned short* curh = B0h; unsigned short* curl = B0l;
    unsigned short* nxth = B1h; unsigned short* nxtl = B1l;
#pragma unroll 1
    for (int j = 5; j >= 0; --j) {
        bf16x8 pbh[4], pbl[4];
#pragma unroll
        for (int f = 0; f < 4; ++f) {
            pbh[f] = ldfrag(curh, wc + l31, f, lh);
            pbl[f] = ldfrag(curl, wc + l31, f, lh);
        }
        f32x16 a2 = mm3(ya_h, ya_l, pbh, pbl);
        float w[16];
        const float cI = CF[2 * j], cX = CF[2 * j + 1];
#pragma unroll
        for (int r = 0; r < 16; ++r)
            w[r] = a2[r] + cX * x_out[r] + (((dmask >> r) & 1) ? cI : 0.f);
        store_cT(nxth, nxtl, w, c_out, rbase);
        unsigned short* th = curh; curh = nxth; nxth = th;
        unsigned short* tl = curl; curl = nxtl; nxtl = tl;
        __syncthreads();   // one barrier per stage (ping-pong)
    }

    // ---- s squarings: P <- P*P; final result written straight to global ----
#pragma unroll 1
    for (int t = 0; t < sexp; ++t) {
        bf16x8 pah[4], pal[4], pbh[4], pbl[4];
#pragma unroll
        for (int f = 0; f < 4; ++f) {
            pah[f] = ldfrag(curh, wr + l31, f, lh);
            pal[f] = ldfrag(curl, wr + l31, f, lh);
        }
        if (diag) {
#pragma unroll
            for (int f = 0; f < 4; ++f) { pbh[f] = pah[f]; pbl[f] = pal[f]; }
        } else {
#pragma unroll
            for (int f = 0; f < 4; ++f) {
                pbh[f] = ldfrag(curh, wc + l31, f, lh);
                pbl[f] = ldfrag(curl, wc + l31, f, lh);
            }
        }
        f32x16 a2 = mm3(pah, pal, pbh, pbl);
        if (t == sexp - 1) {
            // final: fp32 straight from acc (col-contiguous across lanes -> coalesced)
#pragma unroll
            for (int g = 0; g < 4; ++g)
#pragma unroll
                for (int q = 0; q < 4; ++q)
                    out[base + (size_t)(rbase + g * 8 + q) * NB + c_out] = a2[g * 4 + q];
        } else {
            store_cT(nxth, nxtl, (const float*)&a2, c_out, rbase);
            unsigned short* th = curh; curh = nxth; nxth = th;
            unsigned short* tl = curl; curl = nxtl; nxtl = tl;
            __syncthreads();
        }
    }

    if (sexp == 0) {
        // No squarings: P (hi+lo in cur) is the answer; own positions, no barrier needed.
#pragma unroll
        for (int g = 0; g < 4; ++g) {
            unsigned off = swzoff(c_out, (rbase + g * 8) * 2);
            uint2 ph = *(const uint2*)((const char*)curh + off);
            uint2 pl = *(const uint2*)((const char*)curl + off);
            float v0 = bf2f((unsigned short)(ph.x & 0xFFFF)) + bf2f((unsigned short)(pl.x & 0xFFFF));
            float v1 = bf2f((unsigned short)(ph.x >> 16))    + bf2f((unsigned short)(pl.x >> 16));
            float v2 = bf2f((unsigned short)(ph.y & 0xFFFF)) + bf2f((unsigned short)(pl.y & 0xFFFF));
            float v3 = bf2f((unsigned short)(ph.y >> 16))    + bf2f((unsigned short)(pl.y >> 16));
            out[base + (size_t)(rbase + g * 8 + 0) * NB + c_out] = v0;
            out[base + (size_t)(rbase + g * 8 + 1) * NB + c_out] = v1;
            out[base + (size_t)(rbase + g * 8 + 2) * NB + c_out] = v2;
            out[base + (size_t)(rbase + g * 8 + 3) * NB + c_out] = v3;
        }
    }
}

extern "C" void kernel_launch(void* const* d_in, const int* in_sizes, int n_in,
                              void* d_out, int out_size, void* d_ws, size_t ws_size,
                              hipStream_t stream) {
    const float* in = reinterpret_cast<const float*>(d_in[0]);
    float* out = reinterpret_cast<float*>(d_out);
    const int nmat = in_sizes[0] / (NB * NB);
    hipLaunchKernelGGL(spd_expmap_mfma, dim3(nmat), dim3(TPB), 0, stream, in, out);
}

// Round 10
// 299.430 us; speedup vs baseline: 1.4887x; 1.0240x over previous
//
#include <hip/hip_runtime.h>
#include <math.h>

#define NB 64
#define TPB 256

// 1/k! for k = 0..13 (degree-13 Taylor)
__device__ __constant__ float CF[16] = {
    1.0f,
    1.0f,
    0.5f,
    1.6666666666666666e-01f,
    4.1666666666666664e-02f,
    8.3333333333333332e-03f,
    1.3888888888888889e-03f,
    1.9841269841269841e-04f,
    2.4801587301587302e-05f,
    2.7557319223985893e-06f,
    2.7557319223985888e-07f,
    2.5052108385441720e-08f,
    2.0876756987868100e-09f,
    1.6059043836821613e-10f,
    1.1470745597729725e-11f,
    7.6471637318198164e-13f
};

typedef __attribute__((ext_vector_type(8))) short bf16x8;
typedef __attribute__((ext_vector_type(16))) float f32x16;
typedef __attribute__((ext_vector_type(4))) unsigned int u32x4;

#define MFMA32 __builtin_amdgcn_mfma_f32_32x32x16_bf16

// packed split: (x0,x1) -> hi word (bf16(x0)|bf16(x1)<<16), lo word (residuals)
__device__ __forceinline__ void split_pk(float x0, float x1, unsigned& ph, unsigned& pl) {
    unsigned h;
    asm("v_cvt_pk_bf16_f32 %0, %1, %2" : "=v"(h) : "v"(x0), "v"(x1));
    float h0 = __builtin_bit_cast(float, h << 16);
    float h1 = __builtin_bit_cast(float, h & 0xFFFF0000u);
    float r0 = x0 - h0;
    float r1 = x1 - h1;
    unsigned l;
    asm("v_cvt_pk_bf16_f32 %0, %1, %2" : "=v"(l) : "v"(r0), "v"(r1));
    ph = h; pl = l;
}

__device__ __forceinline__ float bf2f(unsigned short h) {
    unsigned u = ((unsigned)h) << 16;
    return __builtin_bit_cast(float, u);
}

// byte offset of (row, byteInRow) in a swizzled 64x64 bf16 LDS matrix (128 B rows)
__device__ __forceinline__ unsigned swzoff(int row, int byteInRow) {
    return (unsigned)(row * 128 + (byteInRow ^ ((row & 7) << 4)));
}

// A/B fragment for v_mfma_f32_32x32x16_bf16, k-step f (k in [16f,16f+16)).
// lane: row = rowbase + (lane&31), k = 16f + 8*(lane>>5) + 0..7  -> 16B read.
// buf must be a compile-time-constant LDS base so the byte base folds into
// the ds_read imm offset (this is the point of the static unroll below).
__device__ __forceinline__ bf16x8 ldfrag(const unsigned short* buf, int row, int f, int lh) {
    const char* p = (const char*)buf + swzoff(row, f * 32 + lh * 16);
    return __builtin_bit_cast(bf16x8, *(const u32x4*)p);
}

// acc = Ahi*Bhi + Alo*Bhi + Ahi*Blo  over K=64 (4 k-steps each)
__device__ __forceinline__ f32x16 mm3(const bf16x8* ah, const bf16x8* al,
                                      const bf16x8* bh, const bf16x8* bl) {
    f32x16 acc = {};
#pragma unroll
    for (int f = 0; f < 4; ++f) acc = MFMA32(ah[f], bh[f], acc, 0, 0, 0);
#pragma unroll
    for (int f = 0; f < 4; ++f) acc = MFMA32(al[f], bh[f], acc, 0, 0, 0);
#pragma unroll
    for (int f = 0; f < 4; ++f) acc = MFMA32(ah[f], bl[f], acc, 0, 0, 0);
    return acc;
}

// Split v[16] into hi/lo bf16 and write TRANSPOSED: value (row r_out, col c_out)
// goes to LDS[c_out][r_out]; 4 consecutive rows per reg-group -> one ds_write_b64.
__device__ __forceinline__ void store_cT(unsigned short* Bh, unsigned short* Bl,
                                         const float* v, int c_out, int rbase) {
#pragma unroll
    for (int g = 0; g < 4; ++g) {
        uint2 wh, wl;
        split_pk(v[g * 4 + 0], v[g * 4 + 1], wh.x, wl.x);
        split_pk(v[g * 4 + 2], v[g * 4 + 3], wh.y, wl.y);
        unsigned off = swzoff(c_out, (rbase + g * 8) * 2);
        *(uint2*)((char*)Bh + off) = wh;
        *(uint2*)((char*)Bl + off) = wl;
    }
}

// One Horner stage: dst = cI*I + cX*X + Y*src   (Y A-frags register-resident)
__device__ __forceinline__ void horner_stage(
    const unsigned short* srch, const unsigned short* srcl,
    unsigned short* dsth, unsigned short* dstl,
    const bf16x8* ya_h, const bf16x8* ya_l,
    const float* x_out, const float* dsel,
    float cI, float cX,
    int wc, int l31, int lh, int c_out, int rbase)
{
    bf16x8 pbh[4], pbl[4];
#pragma unroll
    for (int f = 0; f < 4; ++f) {
        pbh[f] = ldfrag(srch, wc + l31, f, lh);
        pbl[f] = ldfrag(srcl, wc + l31, f, lh);
    }
    f32x16 a2 = mm3(ya_h, ya_l, pbh, pbl);
    float w[16];
#pragma unroll
    for (int r = 0; r < 16; ++r)
        w[r] = fmaf(dsel[r], cI, fmaf(cX, x_out[r], a2[r]));
    store_cT(dsth, dstl, w, c_out, rbase);
}

// One squaring: dst(LDS) = src*src
__device__ __forceinline__ void sq_lds(
    const unsigned short* srch, const unsigned short* srcl,
    unsigned short* dsth, unsigned short* dstl,
    bool diag, int wr, int wc, int l31, int lh, int c_out, int rbase)
{
    bf16x8 pah[4], pal[4], pbh[4], pbl[4];
#pragma unroll
    for (int f = 0; f < 4; ++f) {
        pah[f] = ldfrag(srch, wr + l31, f, lh);
        pal[f] = ldfrag(srcl, wr + l31, f, lh);
    }
    if (diag) {
#pragma unroll
        for (int f = 0; f < 4; ++f) { pbh[f] = pah[f]; pbl[f] = pal[f]; }
    } else {
#pragma unroll
        for (int f = 0; f < 4; ++f) {
            pbh[f] = ldfrag(srch, wc + l31, f, lh);
            pbl[f] = ldfrag(srcl, wc + l31, f, lh);
        }
    }
    f32x16 a2 = mm3(pah, pal, pbh, pbl);
    store_cT(dsth, dstl, (const float*)&a2, c_out, rbase);
}

// Final squaring: out(global fp32) = src*src
__device__ __forceinline__ void sq_global(
    const unsigned short* srch, const unsigned short* srcl,
    float* __restrict__ out, size_t base,
    bool diag, int wr, int wc, int l31, int lh, int c_out, int rbase)
{
    bf16x8 pah[4], pal[4], pbh[4], pbl[4];
#pragma unroll
    for (int f = 0; f < 4; ++f) {
        pah[f] = ldfrag(srch, wr + l31, f, lh);
        pal[f] = ldfrag(srcl, wr + l31, f, lh);
    }
    if (diag) {
#pragma unroll
        for (int f = 0; f < 4; ++f) { pbh[f] = pah[f]; pbl[f] = pal[f]; }
    } else {
#pragma unroll
        for (int f = 0; f < 4; ++f) {
            pbh[f] = ldfrag(srch, wc + l31, f, lh);
            pbl[f] = ldfrag(srcl, wc + l31, f, lh);
        }
    }
    f32x16 a2 = mm3(pah, pal, pbh, pbl);
#pragma unroll
    for (int g = 0; g < 4; ++g)
#pragma unroll
        for (int q = 0; q < 4; ++q)
            out[base + (size_t)(rbase + g * 8 + q) * NB + c_out] = a2[g * 4 + q];
}

// launch_bounds(256,4): (256,5) forces VGPR->48 WITH SCRATCH SPILLS (R8:
// FETCH 131->422MB, WRITE 262->917MB). (256,4) gives clean VGPR<=128 budget;
// runtime occupancy is resource-min (LDS 32KiB -> up to 5 blocks/CU when
// VGPR stays <= 102).
__global__ __launch_bounds__(TPB, 4)
void spd_expmap_mfma(const float* __restrict__ in, float* __restrict__ out)
{
    // Exactly 32 KiB LDS. B0 = X, later P (ping). B1 = scratch/Y, later P (pong).
    __shared__ __align__(16) unsigned short SB[4 * 4096];
    unsigned short* B0h = SB;
    unsigned short* B0l = SB + 4096;
    unsigned short* B1h = SB + 8192;
    unsigned short* B1l = SB + 12288;
    float* fscratch = (float*)B1h;     // 4 floats, dead until Y is stored

    const int tid  = threadIdx.x;
    const int lane = tid & 63;
    const int wv   = tid >> 6;
    const int wr   = (wv >> 1) * 32;   // wave's output row-block
    const int wc   = (wv & 1) * 32;    // wave's output col-block
    const int l31  = lane & 31;
    const int lh   = lane >> 5;
    const int c_out = wc + l31;                 // C/D: col = lane&31
    const int rbase = wr + 4 * lh;              // C/D: row = (reg&3)+8*(reg>>2)+4*(lane>>5)
    const size_t base = (size_t)blockIdx.x * (NB * NB);
    const bool diag = (wr == wc);

    // float diagonal selector (replaces per-use bit tests with 1 fma)
    float dsel[16];
#pragma unroll
    for (int g = 0; g < 4; ++g)
#pragma unroll
        for (int q = 0; q < 4; ++q)
            dsel[g * 4 + q] = (rbase + g * 8 + q == c_out) ? 1.0f : 0.0f;

    // ---- load A (fp32), split hi/lo (packed cvt), store swizzled into B0 ----
    {
        const int r  = tid >> 2;
        const int cb = (tid & 3) * 16;
        const float4* gp = (const float4*)(in + base) + tid * 4;
        float vv[16];
#pragma unroll
        for (int i = 0; i < 4; ++i) {
            float4 t = gp[i];
            vv[i * 4 + 0] = t.x; vv[i * 4 + 1] = t.y;
            vv[i * 4 + 2] = t.z; vv[i * 4 + 3] = t.w;
        }
        unsigned hw[8], lw[8];
#pragma unroll
        for (int i = 0; i < 8; ++i)
            split_pk(vv[2 * i], vv[2 * i + 1], hw[i], lw[i]);
        u32x4 H0 = {hw[0], hw[1], hw[2], hw[3]}, H1 = {hw[4], hw[5], hw[6], hw[7]};
        u32x4 L0 = {lw[0], lw[1], lw[2], lw[3]}, L1 = {lw[4], lw[5], lw[6], lw[7]};
        unsigned o0 = swzoff(r, cb * 2), o1 = swzoff(r, cb * 2 + 16);
        *(u32x4*)((char*)B0h + o0) = H0; *(u32x4*)((char*)B0h + o1) = H1;
        *(u32x4*)((char*)B0l + o0) = L0; *(u32x4*)((char*)B0l + o1) = L1;
    }
    __syncthreads();   // S1: X visible

    // ---- mm1: acc = A*A (split product) + per-wave Frobenius partial ----
    f32x16 acc;
    {
        bf16x8 ah[4], al[4], bh[4], bl[4];
#pragma unroll
        for (int f = 0; f < 4; ++f) {
            ah[f] = ldfrag(B0h, wr + l31, f, lh);
            al[f] = ldfrag(B0l, wr + l31, f, lh);
        }
        if (diag) {
#pragma unroll
            for (int f = 0; f < 4; ++f) { bh[f] = ah[f]; bl[f] = al[f]; }
        } else {
#pragma unroll
            for (int f = 0; f < 4; ++f) {
                bh[f] = ldfrag(B0h, wc + l31, f, lh);
                bl[f] = ldfrag(B0l, wc + l31, f, lh);
            }
        }
        acc = mm3(ah, al, bh, bl);
        float fr = 0.f;
#pragma unroll
        for (int r = 0; r < 16; ++r) fr += acc[r] * acc[r];
#pragma unroll
        for (int off = 32; off; off >>= 1) fr += __shfl_xor(fr, off);
        if (lane == 0) fscratch[wv] = fr;
    }
    __syncthreads();   // S2: partials visible; B0 frag reads drained

    // ||A||_2 <= (sum (A^2)_ij^2)^(1/4); tolerate ||X|| <= 4 (deg-13 remainder ok)
    const float total = fscratch[0] + fscratch[1] + fscratch[2] + fscratch[3];
    __syncthreads();   // S3: all read fscratch before Y overwrites B1
    const float bound = sqrtf(sqrtf(total));
    int sexp = 0;
    if (bound > 4.f) {
        sexp = (int)ceilf(log2f(bound)) - 2;
        if (sexp < 0) sexp = 0;
        if (sexp > 24) sexp = 24;
    }
    const float sc1 = exp2f(-(float)sexp);
    const float sc2 = sc1 * sc1;

    // ---- Y = acc * 4^-s -> split-store into B1 (pre-scaled) ----
    {
        float v[16];
#pragma unroll
        for (int r = 0; r < 16; ++r) v[r] = acc[r] * sc2;
        store_cT(B1h, B1l, v, c_out, rbase);
    }

    // ---- x_out: X at this lane's OWN output positions, scaled in regs ----
    float x_out[16];
#pragma unroll
    for (int g = 0; g < 4; ++g) {
        unsigned off = swzoff(c_out, (rbase + g * 8) * 2);
        uint2 xh = *(const uint2*)((const char*)B0h + off);
        uint2 xl = *(const uint2*)((const char*)B0l + off);
        x_out[g * 4 + 0] = (bf2f((unsigned short)(xh.x & 0xFFFF)) + bf2f((unsigned short)(xl.x & 0xFFFF))) * sc1;
        x_out[g * 4 + 1] = (bf2f((unsigned short)(xh.x >> 16))    + bf2f((unsigned short)(xl.x >> 16)))    * sc1;
        x_out[g * 4 + 2] = (bf2f((unsigned short)(xh.y & 0xFFFF)) + bf2f((unsigned short)(xl.y & 0xFFFF))) * sc1;
        x_out[g * 4 + 3] = (bf2f((unsigned short)(xh.y >> 16))    + bf2f((unsigned short)(xl.y >> 16)))    * sc1;
    }

    // ---- P init = CF[12]*I + CF[13]*X -> B0 (own positions only; X consumed) ----
    {
        float v[16];
#pragma unroll
        for (int r = 0; r < 16; ++r)
            v[r] = fmaf(dsel[r], CF[12], CF[13] * x_out[r]);
        store_cT(B0h, B0l, v, c_out, rbase);
    }
    __syncthreads();   // S4: Y (B1) + P-init (B0) visible

    // ---- resident Y A-side fragments ----
    bf16x8 ya_h[4], ya_l[4];
#pragma unroll
    for (int f = 0; f < 4; ++f) {
        ya_h[f] = ldfrag(B1h, wr + l31, f, lh);
        ya_l[f] = ldfrag(B1l, wr + l31, f, lh);
    }
    __syncthreads();   // S5: Y-frag reads drained before Horner overwrites B1

    // ---- Horner (degree-13, chunk-2), statically unrolled ping-pong ----
    // j = 5,4 / 3,2 / 1,0 ; stage j: P <- (CF[2j]*I + CF[2j+1]*X) + Y*P
#pragma unroll 1
    for (int j = 5; j >= 1; j -= 2) {
        horner_stage(B0h, B0l, B1h, B1l, ya_h, ya_l, x_out, dsel,
                     CF[2 * j], CF[2 * j + 1], wc, l31, lh, c_out, rbase);
        __syncthreads();
        horner_stage(B1h, B1l, B0h, B0l, ya_h, ya_l, x_out, dsel,
                     CF[2 * j - 2], CF[2 * j - 1], wc, l31, lh, c_out, rbase);
        __syncthreads();
    }
    // P now in B0 (6 stages, even count)

    // ---- squarings: sexp-1 in LDS (static ping-pong), final to global ----
    if (sexp == 0) {
        // P (hi+lo in B0) is the answer; own positions, no barrier needed.
#pragma unroll
        for (int g = 0; g < 4; ++g) {
            unsigned off = swzoff(c_out, (rbase + g * 8) * 2);
            uint2 ph = *(const uint2*)((const char*)B0h + off);
            uint2 pl = *(const uint2*)((const char*)B0l + off);
            out[base + (size_t)(rbase + g * 8 + 0) * NB + c_out] = bf2f((unsigned short)(ph.x & 0xFFFF)) + bf2f((unsigned short)(pl.x & 0xFFFF));
            out[base + (size_t)(rbase + g * 8 + 1) * NB + c_out] = bf2f((unsigned short)(ph.x >> 16))    + bf2f((unsigned short)(pl.x >> 16));
            out[base + (size_t)(rbase + g * 8 + 2) * NB + c_out] = bf2f((unsigned short)(ph.y & 0xFFFF)) + bf2f((unsigned short)(pl.y & 0xFFFF));
            out[base + (size_t)(rbase + g * 8 + 3) * NB + c_out] = bf2f((unsigned short)(ph.y >> 16))    + bf2f((unsigned short)(pl.y >> 16));
        }
    } else {
        const int nsq = sexp - 1;   // LDS squarings before the final global one
        int t = 0;
#pragma unroll 1
        while (t < nsq) {
            sq_lds(B0h, B0l, B1h, B1l, diag, wr, wc, l31, lh, c_out, rbase);
            __syncthreads();
            ++t;
            if (t < nsq) {
                sq_lds(B1h, B1l, B0h, B0l, diag, wr, wc, l31, lh, c_out, rbase);
                __syncthreads();
                ++t;
            }
        }
        if (nsq & 1)
            sq_global(B1h, B1l, out, base, diag, wr, wc, l31, lh, c_out, rbase);
        else
            sq_global(B0h, B0l, out, base, diag, wr, wc, l31, lh, c_out, rbase);
    }
}

extern "C" void kernel_launch(void* const* d_in, const int* in_sizes, int n_in,
                              void* d_out, int out_size, void* d_ws, size_t ws_size,
                              hipStream_t stream) {
    const float* in = reinterpret_cast<const float*>(d_in[0]);
    float* out = reinterpret_cast<float*>(d_out);
    const int nmat = in_sizes[0] / (NB * NB);
    hipLaunchKernelGGL(spd_expmap_mfma, dim3(nmat), dim3(TPB), 0, stream, in, out);
}